// Round 4
// baseline (604.995 us; speedup 1.0000x reference)
//
#include <hip/hip_runtime.h>
#include <hip/hip_bf16.h>

#define BB 512
#define SS 50
#define HH 20
#define NN 100000
#define NMC 8          // m-chunks per attention
#define MCH 64         // m-chunk size
#define MT 16          // m register tile
#define NB_MEGA 128    // mega-kernel grid (must be co-resident: 128 << 256 CUs)
#define PBSTRIDE ((size_t)BB*24)

__device__ __forceinline__ float frcp(float x){
#if __has_builtin(__builtin_amdgcn_rcpf)
  return __builtin_amdgcn_rcpf(x);
#else
  return 1.f/x;
#endif
}
__device__ __forceinline__ float fsig(float x){ return frcp(1.f + __expf(-x)); }
__device__ __forceinline__ float ftanh(float x){ return 1.f - 2.f*frcp(1.f + __expf(2.f*x)); }

// ------------------------------------------------------------------
// Fused: embedding gather + edge proj + GNN cell + last/ht snapshot +
// layer-1 QKV for BOTH paths. One block per session b. Also zeroes the
// mega-kernel's grid-barrier cells (stream-ordered before k_mega).
// ------------------------------------------------------------------
__global__ __launch_bounds__(256)
void k_gnnqkv(const int* __restrict__ inputs, const int* __restrict__ category,
              const float* __restrict__ A, const int* __restrict__ mask,
              const float* __restrict__ emb, const float* __restrict__ emb1,
              const float* __restrict__ w_ih, const float* __restrict__ w_hh,
              const float* __restrict__ b_ih, const float* __restrict__ b_hh,
              const float* __restrict__ b_iah, const float* __restrict__ b_oah,
              const float* __restrict__ w_ein, const float* __restrict__ b_ein,
              const float* __restrict__ w_eout, const float* __restrict__ b_eout,
              const float* __restrict__ inw0, const float* __restrict__ inb0,
              const float* __restrict__ inw1, const float* __restrict__ inb1,
              float* __restrict__ q_t, float* __restrict__ k_t, float* __restrict__ v_t,
              int* __restrict__ last, float* __restrict__ ht_item, float* __restrict__ ht_cat,
              int* __restrict__ bar)
{
    __shared__ float sA[SS*2*SS];
    __shared__ float sit[SS*HH], sct[SS*HH], shin[SS*HH], shout[SS*HH];
    __shared__ float sinp[SS*HH], soutp[SS*HH];
    __shared__ float swein[HH*HH], sweout[HH*HH];
    __shared__ float swih[60*40], swhh[60*HH];
    __shared__ float sw0[60*HH], sw1w[60*HH];
    __shared__ float sbein[HH], sbeout[HH], sbih[60], sbhh[60], sbiah[HH], sboah[HH], sb0[60], sb1b[60];
    __shared__ int slast;
    const int b = blockIdx.x, t = threadIdx.x;

    if (b==0 && t<8) bar[t] = 0;

    for (int i=t;i<SS*2*SS;i+=256) sA[i] = A[(size_t)b*SS*2*SS + i];
    for (int i=t;i<HH*HH;i+=256) { swein[i]=w_ein[i]; sweout[i]=w_eout[i]; }
    for (int i=t;i<60*40;i+=256) swih[i]=w_ih[i];
    for (int i=t;i<60*HH;i+=256) { swhh[i]=w_hh[i]; sw0[i]=inw0[i]; sw1w[i]=inw1[i]; }
    if (t<60){ sbih[t]=b_ih[t]; sbhh[t]=b_hh[t]; sb0[t]=inb0[t]; sb1b[t]=inb1[t]; }
    if (t<HH){ sbein[t]=b_ein[t]; sbeout[t]=b_eout[t]; sbiah[t]=b_iah[t]; sboah[t]=b_oah[t]; }
    for (int i=t;i<SS*HH;i+=256){
        int r=i/HH, e=i%HH;
        sit[i]=emb [(size_t)inputs  [b*SS+r]*HH+e];
        sct[i]=emb1[(size_t)category[b*SS+r]*HH+e];
    }
    if (t==0){ int s=0; for (int j=0;j<SS;j++) s+=mask[b*SS+j]; slast=s-1; }
    __syncthreads();

    for (int i=t;i<SS*HH;i+=256){
        int r=i/HH, c=i%HH;
        float si=sbein[c], so=sbeout[c];
        #pragma unroll
        for (int e=0;e<HH;e++){ float hv=sit[r*HH+e]; si+=swein[c*HH+e]*hv; so+=sweout[c*HH+e]*hv; }
        shin[i]=si; shout[i]=so;
    }
    __syncthreads();
    for (int i=t;i<SS*HH;i+=256){
        int r=i/HH, e=i%HH;
        float ai=sbiah[e], ao=sboah[e];
        #pragma unroll 5
        for (int j=0;j<SS;j++){
            ai+=sA[r*2*SS+j]   *shin [j*HH+e];
            ao+=sA[r*2*SS+SS+j]*shout[j*HH+e];
        }
        sinp[i]=ai; soutp[i]=ao;
    }
    __syncthreads();
    float nh[4];
    #pragma unroll
    for (int ii=0;ii<4;ii++){
        int i=t+ii*256;
        if (i<SS*HH){
            int r=i/HH, e=i%HH;
            float gir=sbih[e], gii=sbih[20+e], gin=sbih[40+e];
            #pragma unroll
            for (int k=0;k<HH;k++){
                float vi=sinp[r*HH+k], vo=soutp[r*HH+k];
                gir+=swih[e*40+k]*vi      + swih[e*40+HH+k]*vo;
                gii+=swih[(20+e)*40+k]*vi + swih[(20+e)*40+HH+k]*vo;
                gin+=swih[(40+e)*40+k]*vi + swih[(40+e)*40+HH+k]*vo;
            }
            float ghr=sbhh[e], ghi=sbhh[20+e], ghn=sbhh[40+e];
            #pragma unroll
            for (int k=0;k<HH;k++){
                float hv=sit[r*HH+k];
                ghr+=swhh[e*HH+k]*hv; ghi+=swhh[(20+e)*HH+k]*hv; ghn+=swhh[(40+e)*HH+k]*hv;
            }
            float rr=fsig(gir+ghr), zz=fsig(gii+ghi);
            float nn2=ftanh(gin+rr*ghn);
            nh[ii]=nn2+zz*(sit[i]-nn2);
        }
    }
    __syncthreads();
    #pragma unroll
    for (int ii=0;ii<4;ii++){ int i=t+ii*256; if (i<SS*HH) sit[i]=nh[ii]; }
    __syncthreads();

    if (t<HH)                    ht_item[b*HH+t]      = sit[slast*HH+t];
    else if (t>=32 && t<32+HH)   ht_cat [b*HH+(t-32)] = sct[slast*HH+(t-32)];
    else if (t==63)              last[b]=slast;

    const float SCALE = 0.22360679774997896f;
    for (int oi=t; oi<2*SS*60; oi+=256){
        int p=oi/(SS*60); int rem=oi%(SS*60); int r=rem/60; int c=rem%60;
        const float* src = p? sct  : sit;
        const float* w   = p? sw1w : sw0;
        const float* bb_ = p? sb1b : sb0;
        float acc=bb_[c];
        #pragma unroll
        for (int e=0;e<HH;e++) acc += w[c*HH+e]*src[r*HH+e];
        int which=c/HH, cc=c%HH;
        size_t off=((size_t)(p*SS+r)*BB + b)*HH + cc;
        if (which==0)      q_t[off]=acc*SCALE;
        else if (which==1) k_t[off]=acc;
        else               v_t[off]=acc;
    }
}

// ---------------- grid barrier (all NB_MEGA blocks co-resident) ----------
__device__ __forceinline__ void gridbar(int* bar, int idx){
    __syncthreads();
    if (threadIdx.x==0){
        __threadfence();
        __hip_atomic_fetch_add(&bar[idx], 1, __ATOMIC_RELEASE, __HIP_MEMORY_SCOPE_AGENT);
        while (__hip_atomic_load(&bar[idx], __ATOMIC_ACQUIRE, __HIP_MEMORY_SCOPE_AGENT) < NB_MEGA)
            __builtin_amdgcn_s_sleep(2);
        __threadfence();
    }
    __syncthreads();
}

// merge NMC chunk-partials -> attn out -> out-proj -> residual MLP -> x[20]
__device__ __forceinline__ void merge_res(const float* __restrict__ pbase,
    const float* __restrict__ sow, const float* __restrict__ sob,
    const float* __restrict__ sw1, const float* __restrict__ sb1,
    const float* __restrict__ sw2, const float* __restrict__ sb2,
    float* __restrict__ xo)
{
    float mx=-1e30f;
    #pragma unroll
    for (int mc2=0;mc2<NMC;mc2++) mx=fmaxf(mx, pbase[mc2*PBSTRIDE]);
    float sum=0.f, o[HH];
    #pragma unroll
    for (int e=0;e<HH;e++) o[e]=0.f;
    #pragma unroll
    for (int mc2=0;mc2<NMC;mc2++){
        const float4* pc=(const float4*)(pbase+mc2*PBSTRIDE);
        float4 a=pc[0], b4=pc[1], c4=pc[2], d4=pc[3], e4=pc[4], f4=pc[5];
        float cc=__expf(a.x-mx);
        sum+=a.y*cc;
        o[0]+=a.z*cc;  o[1]+=a.w*cc;
        o[2]+=b4.x*cc; o[3]+=b4.y*cc; o[4]+=b4.z*cc; o[5]+=b4.w*cc;
        o[6]+=c4.x*cc; o[7]+=c4.y*cc; o[8]+=c4.z*cc; o[9]+=c4.w*cc;
        o[10]+=d4.x*cc; o[11]+=d4.y*cc; o[12]+=d4.z*cc; o[13]+=d4.w*cc;
        o[14]+=e4.x*cc; o[15]+=e4.y*cc; o[16]+=e4.z*cc; o[17]+=e4.w*cc;
        o[18]+=f4.x*cc; o[19]+=f4.y*cc;
    }
    float inv=frcp(sum);
    float ao[HH];
    #pragma unroll
    for (int e=0;e<HH;e++) ao[e]=o[e]*inv;
    float mo[HH];
    #pragma unroll
    for (int e=0;e<HH;e++){
        float acc=sob[e];
        #pragma unroll
        for (int f=0;f<HH;f++) acc+=sow[e*HH+f]*ao[f];
        mo[e]=acc;
    }
    float u[HH];
    #pragma unroll
    for (int g=0;g<HH;g++){
        float acc=sb1[g];
        #pragma unroll
        for (int f=0;f<HH;f++) acc+=sw1[g*HH+f]*mo[f];
        u[g]=fmaxf(acc,0.f);
    }
    #pragma unroll
    for (int e=0;e<HH;e++){
        float acc=mo[e]+sb2[e];
        #pragma unroll
        for (int g=0;g<HH;g++) acc+=sw2[e*HH+g]*u[g];
        xo[e]=acc;
    }
}

// one attention task: (si, p, rc in {0,1} rows of 256, mc in [0,8))
__device__ __forceinline__ void attn_task(const float* __restrict__ q_t,
    const float* __restrict__ k_t, const float* __restrict__ v_t,
    float* __restrict__ pbuf, float* __restrict__ sk, float* __restrict__ sv,
    int si, int p, int rc, int mc, int t)
{
    const size_t base=(size_t)(p*SS+si)*BB;
    {
        const float4* kb=(const float4*)(k_t+(base+(size_t)mc*MCH)*HH);
        const float4* vb=(const float4*)(v_t+(base+(size_t)mc*MCH)*HH);
        float4* sk4=(float4*)sk; float4* sv4=(float4*)sv;
        for (int i=t;i<MCH*HH/4;i+=256){ sk4[i]=kb[i]; sv4[i]=vb[i]; }
    }
    __syncthreads();
    const int row = rc*256 + t;
    float4 q[5];
    {
        const float4* qp=(const float4*)(q_t+(base+row)*HH);
        #pragma unroll
        for (int i=0;i<5;i++) q[i]=qp[i];
    }
    float4 o[5];
    #pragma unroll
    for (int i=0;i<5;i++) o[i]=make_float4(0.f,0.f,0.f,0.f);
    float mx=-1e30f, sm=0.f;

    for (int mt0=0; mt0<MCH; mt0+=MT){
        float sc[MT]; float tm=-1e30f;
        #pragma unroll
        for (int j=0;j<MT;j++){
            const float4* kr=(const float4*)(sk+(mt0+j)*HH);
            float a0=0.f;
            #pragma unroll
            for (int i=0;i<5;i++){
                float4 kv=kr[i];
                a0+=q[i].x*kv.x+q[i].y*kv.y+q[i].z*kv.z+q[i].w*kv.w;
            }
            sc[j]=a0; tm=fmaxf(tm,a0);
        }
        float nm=fmaxf(mx,tm);
        float c=__expf(mx-nm);
        sm*=c;
        #pragma unroll
        for (int i=0;i<5;i++){ o[i].x*=c; o[i].y*=c; o[i].z*=c; o[i].w*=c; }
        mx=nm;
        #pragma unroll
        for (int j=0;j<MT;j++){
            float pe=__expf(sc[j]-nm);
            sm+=pe;
            const float4* vr=(const float4*)(sv+(mt0+j)*HH);
            #pragma unroll
            for (int i=0;i<5;i++){
                float4 vv=vr[i];
                o[i].x+=pe*vv.x; o[i].y+=pe*vv.y; o[i].z+=pe*vv.z; o[i].w+=pe*vv.w;
            }
        }
    }
    float* pb = pbuf + (((size_t)(p*SS+si)*NMC+mc)*BB + row)*24;
    float4* w0=(float4*)pb;
    w0[0]=make_float4(mx,sm,o[0].x,o[0].y);
    w0[1]=make_float4(o[0].z,o[0].w,o[1].x,o[1].y);
    w0[2]=make_float4(o[1].z,o[1].w,o[2].x,o[2].y);
    w0[3]=make_float4(o[2].z,o[2].w,o[3].x,o[3].y);
    w0[4]=make_float4(o[3].z,o[3].w,o[4].x,o[4].y);
    w0[5]=make_float4(o[4].z,o[4].w,0.f,0.f);
    __syncthreads();
}

// ------------------------------------------------------------------
// Mega-kernel: flags -> attn L1 -> |bar| -> fin+QKV L2 -> |bar| ->
// attn L2 -> |bar| -> fin L2 + mix + head -> final_
// ------------------------------------------------------------------
__global__ __launch_bounds__(256)
void k_mega(const float* __restrict__ q_t0, float* __restrict__ q_t,
            float* __restrict__ k_t, float* __restrict__ v_t,
            float* __restrict__ pbuf, const int* __restrict__ last,
            const float* __restrict__ ht_item, const float* __restrict__ ht_cat,
            const float* __restrict__ ow0, const float* __restrict__ ob0,
            const float* __restrict__ w10, const float* __restrict__ b10,
            const float* __restrict__ w20, const float* __restrict__ b20,
            const float* __restrict__ iw0, const float* __restrict__ ib0,
            const float* __restrict__ ow1, const float* __restrict__ ob1,
            const float* __restrict__ w11, const float* __restrict__ b11,
            const float* __restrict__ w21, const float* __restrict__ b21,
            const float* __restrict__ iw1, const float* __restrict__ ib1,
            const float* __restrict__ mem_M, const float* __restrict__ mem_Wa,
            const float* __restrict__ mem_fc,
            const float* __restrict__ wc, const float* __restrict__ bc,
            const float* __restrict__ wp, const float* __restrict__ bp,
            float* __restrict__ final_, int* __restrict__ bar)
{
    __shared__ float smem[6400];
    __shared__ int slast_c[BB];
    __shared__ int snf[SS];
    __shared__ int slist[SS];
    __shared__ int sns;
    const int t = threadIdx.x, bid = blockIdx.x;

    // ---- phase A: needed-s set (computed redundantly & identically per block)
    for (int i=t;i<BB;i+=256) slast_c[i]=last[i];
    if (t<SS) snf[t]=0;
    __syncthreads();
    for (int i=t;i<BB;i+=256) atomicOr(&snf[slast_c[i]],1);
    __syncthreads();
    if (t==0){ int c=0; for (int s=0;s<SS;s++) if (snf[s]) slist[c++]=s; sns=c; }
    __syncthreads();
    const int ns = sns;

    // ---- phase B: layer-1 attention partials
    {
        const int T = ns*2*16;     // si x p x (rc2 * mc8)
        float* sk = smem; float* sv = smem + MCH*HH;
        for (int task=bid; task<T; task+=NB_MEGA){
            int si=slist[task/32]; int rem=task%32;
            int p=rem>>4, rc=(rem>>3)&1, mc=rem&7;
            attn_task(q_t0, k_t, v_t, pbuf, sk, sv, si, p, rc, mc, t);
        }
    }
    gridbar(bar, 0);

    // ---- phase C: layer-1 finish + layer-2 QKV
    {
        const int T = ns*2*2;      // si x p x bc
        float* sow=smem; float* sw1=smem+400; float* sw2=smem+800; float* siw=smem+1200;
        float* sob=smem+2400; float* sb1=smem+2420; float* sb2=smem+2440; float* sib=smem+2460;
        for (int task=bid; task<T; task+=NB_MEGA){
            int si=slist[task/4]; int p=(task>>1)&1; int bc=task&1;
            const float* OW=p?ow1:ow0; const float* OB=p?ob1:ob0;
            const float* W1=p?w11:w10; const float* B1=p?b11:b10;
            const float* W2=p?w21:w20; const float* B2=p?b21:b20;
            const float* IW=p?iw1:iw0; const float* IB=p?ib1:ib0;
            __syncthreads();
            for (int i=t;i<400;i+=256){ sow[i]=OW[i]; sw1[i]=W1[i]; sw2[i]=W2[i]; }
            for (int i=t;i<1200;i+=256) siw[i]=IW[i];
            if (t<20){ sob[t]=OB[t]; sb1[t]=B1[t]; sb2[t]=B2[t]; }
            if (t<60) sib[t]=IB[t];
            __syncthreads();
            const int b = bc*256 + t;
            const float* pbase = pbuf + (((size_t)(p*SS+si)*NMC)*BB + b)*24;
            float xo[HH];
            merge_res(pbase, sow,sob,sw1,sb1,sw2,sb2, xo);
            const float SCALE = 0.22360679774997896f;
            size_t off0=((size_t)(p*SS+si)*BB + b)*HH;
            #pragma unroll
            for (int c=0;c<HH;c++){
                float aq=sib[c], ak=sib[20+c], av=sib[40+c];
                #pragma unroll
                for (int e=0;e<HH;e++){ float xv=xo[e]; aq+=siw[c*HH+e]*xv; ak+=siw[(20+c)*HH+e]*xv; av+=siw[(40+c)*HH+e]*xv; }
                q_t[off0+c]=aq*SCALE; k_t[off0+c]=ak; v_t[off0+c]=av;
            }
        }
    }
    gridbar(bar, 1);

    // ---- phase D: layer-2 attention partials
    {
        const int T = ns*2*16;
        float* sk = smem; float* sv = smem + MCH*HH;
        for (int task=bid; task<T; task+=NB_MEGA){
            int si=slist[task/32]; int rem=task%32;
            int p=rem>>4, rc=(rem>>3)&1, mc=rem&7;
            attn_task(q_t, k_t, v_t, pbuf, sk, sv, si, p, rc, mc, t);
        }
    }
    gridbar(bar, 2);

    // ---- phase E: layer-2 finish + a-mix + memory head -> final_
    {
        // smem layout (floats):
        // 0 mem_M[200] | 200 mem_Wa[800] | 1000 mem_fc[400] | 1400 wc[1200]
        // 2600 wp[1200] | 3800 bc[20] | 3820 bp[20]
        // 3840 + p*1260: ow[400] w1[400] w2[400] ob[20] b1[20] b2[20]
        for (int task=bid; task<2; task+=NB_MEGA){
            __syncthreads();
            for (int i=t;i<200;i+=256)  smem[i]     =mem_M[i];
            for (int i=t;i<800;i+=256)  smem[200+i] =mem_Wa[i];
            for (int i=t;i<400;i+=256)  smem[1000+i]=mem_fc[i];
            for (int i=t;i<1200;i+=256){ smem[1400+i]=wc[i]; smem[2600+i]=wp[i]; }
            if (t<20){ smem[3800+t]=bc[t]; smem[3820+t]=bp[t]; }
            for (int i=t;i<400;i+=256){
                smem[3840+i]=ow0[i]; smem[3840+400+i]=w10[i]; smem[3840+800+i]=w20[i];
                smem[5100+i]=ow1[i]; smem[5100+400+i]=w11[i]; smem[5100+800+i]=w21[i];
            }
            if (t<20){
                smem[3840+1200+t]=ob0[t]; smem[3840+1220+t]=b10[t]; smem[3840+1240+t]=b20[t];
                smem[5100+1200+t]=ob1[t]; smem[5100+1220+t]=b11[t]; smem[5100+1240+t]=b21[t];
            }
            __syncthreads();
            const int b = task*256 + t;
            const int sb = slast_c[b];
            float a[40];
            {
                const float* pb0 = pbuf + (((size_t)(0*SS+sb)*NMC)*BB + b)*24;
                float xo[HH];
                merge_res(pb0, smem+3840, smem+3840+1200, smem+3840+400, smem+3840+1220,
                          smem+3840+800, smem+3840+1240, xo);
                #pragma unroll
                for (int e=0;e<HH;e++) a[e] = 0.52f*xo[e] + 0.48f*ht_item[b*HH+e];
            }
            {
                const float* pb1 = pbuf + (((size_t)(1*SS+sb)*NMC)*BB + b)*24;
                float xo[HH];
                merge_res(pb1, smem+5100, smem+5100+1200, smem+5100+400, smem+5100+1220,
                          smem+5100+800, smem+5100+1240, xo);
                #pragma unroll
                for (int e=0;e<HH;e++) a[20+e] = 0.52f*xo[e] + 0.48f*ht_cat[b*HH+e];
            }
            float t20[20];
            #pragma unroll
            for (int j=0;j<20;j++){
                float acc=0.f;
                #pragma unroll
                for (int k=0;k<40;k++) acc+=a[k]*smem[200+k*20+j];
                t20[j]=acc;
            }
            float lg[10]; float mxv=-1e30f;
            #pragma unroll
            for (int c=0;c<10;c++){
                float acc=0.f;
                #pragma unroll
                for (int j=0;j<20;j++) acc+=t20[j]*smem[c*20+j];
                lg[c]=acc; mxv=fmaxf(mxv,acc);
            }
            float se=0.f;
            #pragma unroll
            for (int c=0;c<10;c++){ lg[c]=__expf(lg[c]-mxv); se+=lg[c]; }
            float inv=frcp(se);
            #pragma unroll
            for (int c=0;c<10;c++) lg[c]*=inv;
            float am[20];
            #pragma unroll
            for (int j=0;j<20;j++){
                float acc=0.f;
                #pragma unroll
                for (int c=0;c<10;c++) acc+=lg[c]*smem[c*20+j];
                am[j]=acc;
            }
            float reps[20];
            #pragma unroll
            for (int j2=0;j2<20;j2++){
                float acc=0.f;
                #pragma unroll
                for (int j=0;j<20;j++) acc+=am[j]*smem[1000+j*20+j2];
                reps[j2]=ftanh(acc);
            }
            #pragma unroll
            for (int e=0;e<HH;e++){
                float c1=smem[3800+e], c2=smem[3820+e];
                #pragma unroll
                for (int k=0;k<40;k++){ c1+=a[k]*smem[1400+e*60+k]; c2+=a[k]*smem[2600+e*60+k]; }
                #pragma unroll
                for (int k=0;k<20;k++){ c1+=reps[k]*smem[1400+e*60+40+k]; c2+=reps[k]*smem[2600+e*60+40+k]; }
                final_[b*HH+e]=fsig(c1)*c2;
            }
        }
    }
}

__global__ __launch_bounds__(256)
void k_scores(const float* __restrict__ final_, const float* __restrict__ emb,
              float* __restrict__ out)
{
    int node = blockIdx.x*256 + threadIdx.x;
    if (node >= NN-1) return;
    float4 er[5];
    const float4* e4 = (const float4*)(emb + ((size_t)node + 1)*HH);
    #pragma unroll
    for (int i=0;i<5;i++) er[i]=e4[i];
    float* op = out + node;
    for (int b = 0; b < BB; b++) {
        const float4* fb = (const float4*)(final_ + b*HH);
        float acc = 0.f;
        #pragma unroll
        for (int i=0;i<5;i++){
            float4 f=fb[i];
            acc += f.x*er[i].x + f.y*er[i].y + f.z*er[i].z + f.w*er[i].w;
        }
        *op = acc;
        op += (NN-1);
    }
}

extern "C" void kernel_launch(void* const* d_in, const int* in_sizes, int n_in,
                              void* d_out, int out_size, void* d_ws, size_t ws_size,
                              hipStream_t stream) {
    const int*   inputs   = (const int*)  d_in[0];
    const int*   category = (const int*)  d_in[1];
    const float* A        = (const float*)d_in[2];
    const int*   mask     = (const int*)  d_in[3];
    const float* emb      = (const float*)d_in[4];
    const float* emb1     = (const float*)d_in[5];
    const float* w_ih     = (const float*)d_in[6];
    const float* w_hh     = (const float*)d_in[7];
    const float* b_ih     = (const float*)d_in[8];
    const float* b_hh     = (const float*)d_in[9];
    const float* b_iah    = (const float*)d_in[10];
    const float* b_oah    = (const float*)d_in[11];
    const float* w_ein    = (const float*)d_in[12];
    const float* b_ein    = (const float*)d_in[13];
    const float* w_eout   = (const float*)d_in[14];
    const float* b_eout   = (const float*)d_in[15];
    const float* mha_in_w  = (const float*)d_in[16];
    const float* mha_in_b  = (const float*)d_in[17];
    const float* mha_out_w = (const float*)d_in[18];
    const float* mha_out_b = (const float*)d_in[19];
    const float* mha1_in_w  = (const float*)d_in[20];
    const float* mha1_in_b  = (const float*)d_in[21];
    const float* mha1_out_w = (const float*)d_in[22];
    const float* mha1_out_b = (const float*)d_in[23];
    const float* rn_w1 = (const float*)d_in[24];
    const float* rn_b1 = (const float*)d_in[25];
    const float* rn_w2 = (const float*)d_in[26];
    const float* rn_b2 = (const float*)d_in[27];
    const float* rn1_w1 = (const float*)d_in[28];
    const float* rn1_b1 = (const float*)d_in[29];
    const float* rn1_w2 = (const float*)d_in[30];
    const float* rn1_b2 = (const float*)d_in[31];
    const float* mem_M  = (const float*)d_in[32];
    const float* mem_Wa = (const float*)d_in[33];
    const float* mem_fc = (const float*)d_in[34];
    const float* wc = (const float*)d_in[35];
    const float* bc = (const float*)d_in[36];
    const float* wp = (const float*)d_in[37];
    const float* bp = (const float*)d_in[38];
    float* out = (float*)d_out;

    float* W = (float*)d_ws;
    float* q_t     = W;                    // 1,024,000
    float* k_t     = W + 1024000;
    float* v_t     = W + 2048000;
    float* pbuf    = W + 3072000;          // 9,830,400
    float* ht_item = W + 12902400;         // 10,240
    float* ht_cat  = W + 12912640;         // 10,240
    float* final_  = W + 12922880;         // 10,240
    int*   last    = (int*)(W + 12933120); // 512
    int*   bar     = (int*)(W + 12933632); // 8

    // 1. fused gather + GNN + last/ht + layer-1 QKV (zeroes barrier cells)
    k_gnnqkv<<<BB, 256, 0, stream>>>(inputs, category, A, mask, emb, emb1,
                                     w_ih, w_hh, b_ih, b_hh, b_iah, b_oah,
                                     w_ein, b_ein, w_eout, b_eout,
                                     mha_in_w, mha_in_b, mha1_in_w, mha1_in_b,
                                     q_t, k_t, v_t, last, ht_item, ht_cat, bar);
    // 2. mega: flags -> attnL1 -> finqkv -> attnL2 -> fin+head
    k_mega<<<NB_MEGA, 256, 0, stream>>>(q_t, q_t, k_t, v_t, pbuf, last,
        ht_item, ht_cat,
        mha_out_w, mha_out_b, rn_w1, rn_b1, rn_w2, rn_b2, mha_in_w, mha_in_b,
        mha1_out_w, mha1_out_b, rn1_w1, rn1_b1, rn1_w2, rn1_b2, mha1_in_w, mha1_in_b,
        mem_M, mem_Wa, mem_fc, wc, bc, wp, bp, final_, bar);
    // 3. scores = final @ emb[1:].T
    k_scores<<<(NN-1+255)/256, 256, 0, stream>>>(final_, emb, out);
}